// Round 11
// baseline (224.094 us; speedup 1.0000x reference)
//
#include <hip/hip_runtime.h>
#include <stdint.h>

// GaussianKernelSimilarity: z[8192,1024] f32, expert_keys[4096,1024] f32
// out0 = exp(-max(|z|^2+|e|^2-2 z.e, 0)/2)  [8192,4096]
// out1 = softmax(out0, axis=-1) @ expert_keys [8192,1024]
//
// Round 11: write-volume attack. Evidence: 6 GEMM1 structures all pinned at
// 1.5-1.8 TB/s write throughput -> write-drain bound. Changes vs round 9:
//  - GEMM1 no longer writes Wb (saves 64 MB of its 200 MB write stream);
//    sim stores are plain (not nt) so sim stays L3-resident.
//  - GEMM2 (gemm2_sim) reads sim f32 directly from L3, fusing
//    es=exp(sim)->bf16 into reg->LDS A-staging (swizzled ds_write).
//    BN=256 caps sim re-reads at 4x (512 MB cache traffic = old Wb+B).
//  - K-loop/epilogue of GEMM1 = round 9 exactly (BK=64, swizzle, 8 waves,
//    no atomics, L2 super-tiles).

#define M_TOK 8192
#define N_EXP 4096
#define D_DIM 1024

typedef __attribute__((ext_vector_type(4))) float f32x4;
typedef __attribute__((ext_vector_type(8))) short short8;
typedef __attribute__((ext_vector_type(4))) unsigned short u16x4;
typedef unsigned short u16;
typedef unsigned int u32;

__device__ __forceinline__ u16 f32_to_bf16(float f) {
  u32 u = __builtin_bit_cast(u32, f);
  u += 0x7fff + ((u >> 16) & 1);   // round-to-nearest-even
  return (u16)(u >> 16);
}

__device__ __forceinline__ void async16(const void* g, void* l) {
  __builtin_amdgcn_global_load_lds((__attribute__((address_space(1))) void*)(g),
                                   (__attribute__((address_space(3))) void*)(l),
                                   16, 0, 0);
}

// ---- prep: f32 -> bf16 convert + row |.|^2 for BOTH z and e (one launch) --
__global__ __launch_bounds__(256) void prep_convert2(const float* __restrict__ zsrc,
                                                     const float* __restrict__ esrc,
                                                     u16* __restrict__ zdst,
                                                     u16* __restrict__ edst,
                                                     float* __restrict__ zsq,
                                                     float* __restrict__ esq) {
  int row = blockIdx.x;
  const float* src;
  u16* dst;
  float* sq;
  if (row < M_TOK) {
    src = zsrc + (size_t)row * D_DIM;
    dst = zdst + (size_t)row * D_DIM;
    sq = zsq + row;
  } else {
    int r = row - M_TOK;
    src = esrc + (size_t)r * D_DIM;
    dst = edst + (size_t)r * D_DIM;
    sq = esq + r;
  }
  int t = threadIdx.x;                       // 256 threads, 4 elems each
  const float4 v = ((const float4*)src)[t];
  ushort4 h;
  h.x = f32_to_bf16(v.x); h.y = f32_to_bf16(v.y);
  h.z = f32_to_bf16(v.z); h.w = f32_to_bf16(v.w);
  ((ushort4*)dst)[t] = h;
  float p = v.x * v.x + v.y * v.y + v.z * v.z + v.w * v.w;
#pragma unroll
  for (int off = 1; off < 64; off <<= 1) p += __shfl_xor(p, off, 64);
  __shared__ float partial[4];
  if ((t & 63) == 0) partial[t >> 6] = p;
  __syncthreads();
  if (t == 0) *sq = partial[0] + partial[1] + partial[2] + partial[3];
}

// ---- bf16 transpose: eb[4096][1024] -> ebT[1024][4096] --------------------
__global__ __launch_bounds__(256) void transpose_bf16(const u16* __restrict__ src,
                                                      u16* __restrict__ dst) {
  __shared__ u16 tile[64][65];
  int e0 = blockIdx.x * 64;
  int d0 = blockIdx.y * 64;
  int t = threadIdx.x;
  int lr = t >> 4;
  int lc = (t & 15) * 4;
#pragma unroll
  for (int r8 = 0; r8 < 4; ++r8) {
    int row = lr + r8 * 16;
    ushort4 v = *(const ushort4*)(src + (size_t)(e0 + row) * D_DIM + d0 + lc);
    tile[row][lc + 0] = v.x; tile[row][lc + 1] = v.y;
    tile[row][lc + 2] = v.z; tile[row][lc + 3] = v.w;
  }
  __syncthreads();
#pragma unroll
  for (int r8 = 0; r8 < 4; ++r8) {
    int dl = lr + r8 * 16;
    ushort4 v;
    v.x = tile[lc + 0][dl]; v.y = tile[lc + 1][dl];
    v.z = tile[lc + 2][dl]; v.w = tile[lc + 3][dl];
    *(ushort4*)(dst + (size_t)(d0 + dl) * N_EXP + e0 + lc) = v;
  }
}

// ---- rowsum reduce: rowsum[r] = sum_j rs_part[j][r], j in [0,128) ---------
__global__ __launch_bounds__(256) void rowsum_reduce(const float* __restrict__ part,
                                                     float* __restrict__ rowsum) {
  int r = blockIdx.x * 256 + threadIdx.x;    // 32 blocks x 256 = 8192 rows
  float s = 0.f;
#pragma unroll 8
  for (int j = 0; j < 128; ++j) s += part[(size_t)j * M_TOK + r];
  rowsum[r] = s;
}

// ---- gemm_bt: round-9 kernel (GEMM1 + fallback GEMM2) ---------------------
// 128x128 tile, BK=64, 512 threads = 8 waves (2M x 4N), dbuf 64 KiB.
// LDS XOR-swizzle on read, pre-swizzled global source for global_load_lds.
// SWAPPED operands mfma(bf, af, acc):
//   m-row = lane&15 (+mi*16+wr*64), n-col = (lane>>4)*4+reg (+ni*16+wc*32)
// EPI=1: XCD stripe + 8m x 4n super-tiles; LDS-transposed full-line sim
//   stores (PLAIN, so sim stays L3-resident for gemm2_sim); es=exp(sim) once
//   -> optional Wb + partial rowsum rs_part[slot][row] (no atomics).
// EPI=0: store acc * (1/scale[row]).
template <int EPI>
__global__ __launch_bounds__(512, 4) void gemm_bt(const u16* __restrict__ A,
                                                  const u16* __restrict__ Bt,
                                                  int Mdim, int Ndim, int Kdim,
                                                  float* __restrict__ out, int ldo,
                                                  const float* __restrict__ a_sq,
                                                  const float* __restrict__ b_sq,
                                                  float* __restrict__ rs_part,
                                                  u16* __restrict__ wb,
                                                  const float* __restrict__ scale) {
  constexpr int BM = 128, BN = 128, BK = 64;
  __shared__ __align__(16) u16 smA[2 * BM * BK];   // 32 KiB
  __shared__ __align__(16) u16 smB[2 * BN * BK];   // 32 KiB

  const int wg = blockIdx.x;
  int m0, n0, ntile = 0;
  if (EPI == 1) {
    const int xcd = wg & 7;
    const int idx = wg >> 3;
    const int sup = idx >> 5;
    const int mloc = (idx & 31) >> 2;
    const int nloc = idx & 3;
    m0 = (xcd * 8 + mloc) * BM;
    ntile = sup * 4 + nloc;
    n0 = ntile * BN;
  } else {
    const int nTilesN = Ndim / BN;
    const int nwg = (Mdim / BM) * nTilesN;
    const int cpx = nwg >> 3;
    const int swz = (wg & 7) * cpx + (wg >> 3);
    m0 = (swz / nTilesN) * BM;
    n0 = (swz % nTilesN) * BN;
  }

  const int t = threadIdx.x;
  const int l = t & 63;
  const int w = t >> 6;          // wave 0..7
  const int wr = w >> 2;         // 0..1 (M)
  const int wc = w & 3;          // 0..3 (N)
  const int lr8 = l >> 3;
  const int cswz = (((l & 7) ^ lr8) << 3);
  const int s0 = w * 2, s1 = w * 2 + 1;
  const int str0 = s0 * 8 + lr8, str1 = s1 * 8 + lr8;

  f32x4 acc[4][2];
#pragma unroll
  for (int i = 0; i < 4; ++i)
#pragma unroll
    for (int j = 0; j < 2; ++j) acc[i][j] = (f32x4){0.f, 0.f, 0.f, 0.f};

  const int nIter = Kdim / BK;
  async16(A + (size_t)(m0 + str0) * Kdim + cswz, smA + s0 * 512);
  async16(A + (size_t)(m0 + str1) * Kdim + cswz, smA + s1 * 512);
  async16(Bt + (size_t)(n0 + str0) * Kdim + cswz, smB + s0 * 512);
  async16(Bt + (size_t)(n0 + str1) * Kdim + cswz, smB + s1 * 512);
  __syncthreads();

  int cur = 0;
  for (int it = 0; it < nIter; ++it) {
    if (it + 1 < nIter) {
      const int k0 = (it + 1) * BK;
      const int nb = (cur ^ 1) * 8192;
      async16(A + (size_t)(m0 + str0) * Kdim + k0 + cswz, smA + nb + s0 * 512);
      async16(A + (size_t)(m0 + str1) * Kdim + k0 + cswz, smA + nb + s1 * 512);
      async16(Bt + (size_t)(n0 + str0) * Kdim + k0 + cswz, smB + nb + s0 * 512);
      async16(Bt + (size_t)(n0 + str1) * Kdim + k0 + cswz, smB + nb + s1 * 512);
    }
    const int cbase = cur * 8192;
#pragma unroll
    for (int ks = 0; ks < 2; ++ks) {
      short8 af[4], bf[2];
      const int lrow = l & 15;
      const int kb = ks * 64 + ((l >> 4) << 4);
#pragma unroll
      for (int mi = 0; mi < 4; ++mi) {
        int row = wr * 64 + mi * 16 + lrow;
        int addr = row * 128 + (kb ^ ((row & 7) << 4));
        af[mi] = *(const short8*)(smA + cbase + (addr >> 1));
      }
#pragma unroll
      for (int ni = 0; ni < 2; ++ni) {
        int row = wc * 32 + ni * 16 + lrow;
        int addr = row * 128 + (kb ^ ((row & 7) << 4));
        bf[ni] = *(const short8*)(smB + cbase + (addr >> 1));
      }
#pragma unroll
      for (int mi = 0; mi < 4; ++mi)
#pragma unroll
        for (int ni = 0; ni < 2; ++ni)
          acc[mi][ni] = __builtin_amdgcn_mfma_f32_16x16x32_bf16(
              bf[ni], af[mi], acc[mi][ni], 0, 0, 0);
    }
    __syncthreads();
    cur ^= 1;
  }

  const int lcol = l & 15;
  const int rgrp = l >> 4;
  if (EPI == 1) {
    float* ldsT = ((float*)smA) + w * (16 * 36);   // wave-private scratch
    const int rr = l >> 3;
    const int c4 = (l & 7) * 4;
    const int slot = ntile * 4 + wc;
#pragma unroll
    for (int mi = 0; mi < 4; ++mi) {
      int grow = m0 + wr * 64 + mi * 16 + lcol;
      float zq = a_sq[grow];
#pragma unroll
      for (int ni = 0; ni < 2; ++ni) {
        int ncol = n0 + wc * 32 + ni * 16 + rgrp * 4;
        f32x4 eqv = *(const f32x4*)(b_sq + ncol);
        f32x4 simv;
#pragma unroll
        for (int r = 0; r < 4; ++r) {
          float dist2 = fmaxf(zq + eqv[r] - 2.0f * acc[mi][ni][r], 0.0f);
          simv[r] = __expf(-0.5f * dist2);
        }
        *(f32x4*)(ldsT + lcol * 36 + ni * 16 + rgrp * 4) = simv;
      }
      asm volatile("s_waitcnt lgkmcnt(0)" ::: "memory");
#pragma unroll
      for (int pass = 0; pass < 2; ++pass) {
        int rrow = pass * 8 + rr;
        f32x4 sv = *(const f32x4*)(ldsT + rrow * 36 + c4);
        int growr = m0 + wr * 64 + mi * 16 + rrow;
        size_t gbase = (size_t)growr * ldo + (n0 + wc * 32 + c4);
        *(f32x4*)(out + gbase) = sv;            // plain store: keep L3-warm
        f32x4 es;
#pragma unroll
        for (int r = 0; r < 4; ++r) es[r] = __expf(sv[r]);
        if (wb) {
          u16x4 wv;
          wv.x = f32_to_bf16(es[0]); wv.y = f32_to_bf16(es[1]);
          wv.z = f32_to_bf16(es[2]); wv.w = f32_to_bf16(es[3]);
          *(u16x4*)(wb + gbase) = wv;
        }
        float p = es[0] + es[1] + es[2] + es[3];
        p += __shfl_xor(p, 1, 64);
        p += __shfl_xor(p, 2, 64);
        p += __shfl_xor(p, 4, 64);
        if ((l & 7) == 0) rs_part[(size_t)slot * M_TOK + growr] = p;
      }
    }
  } else {
#pragma unroll
    for (int mi = 0; mi < 4; ++mi) {
      int grow = m0 + wr * 64 + mi * 16 + lcol;
      float s = scale ? (1.0f / scale[grow]) : 1.0f;
#pragma unroll
      for (int ni = 0; ni < 2; ++ni) {
        int ncol = n0 + wc * 32 + ni * 16 + rgrp * 4;
        f32x4 v = acc[mi][ni] * s;
        *(f32x4*)(out + (size_t)grow * ldo + ncol) = v;
      }
    }
  }
}

// ---- gemm2_sim: wout = (exp(sim) @ E) / rowsum ----------------------------
// A = sim f32 [M, 4096] read from L3; exp+bf16 fused into reg->LDS staging
// (ds_write to swizzled dest). B = ebT via async16 (pre-swizzled source).
// BM=128, BN=256, BK=64, 512 thr = 8 waves (2M x 4N), per-wave 64x64,
// acc[4][4]. LDS 96 KiB (A dbuf 32K + B dbuf 64K) -> 1 block/CU.
// Grid 64m x 4n = 256 blocks; sim re-read 4x (~512 MB cache traffic).
__global__ __launch_bounds__(512, 2) void gemm2_sim(const float* __restrict__ simf,
                                                    const u16* __restrict__ Bt,
                                                    float* __restrict__ out,
                                                    const float* __restrict__ rowsum) {
  constexpr int BM = 128, BN = 256, BK = 64;
  constexpr int K = N_EXP;                  // 4096
  __shared__ __align__(16) u16 smA[2 * BM * BK];   // 32 KiB
  __shared__ __align__(16) u16 smB[2 * BN * BK];   // 64 KiB

  const int wg = blockIdx.x;                // 256 blocks
  const int swz = (wg & 7) * 32 + (wg >> 3);
  const int m0 = (swz >> 2) * BM;
  const int n0 = (swz & 3) * BN;

  const int t = threadIdx.x;
  const int l = t & 63;
  const int w = t >> 6;
  const int wr = w >> 2;        // 0..1
  const int wc = w & 3;         // 0..3 (64 cols each)
  const int lr8 = l >> 3;
  const int cswz = (((l & 7) ^ lr8) << 3);
  // A staging: thread t -> row t>>2, col quarter t&3 (16 f32)
  const int arow = t >> 2;
  const int acolb = (t & 3) * 32;           // byte offset of 16-elem group
  const int asw = (arow & 7) << 4;
  const size_t agbase = (size_t)(m0 + arow) * K + (t & 3) * 16;

  f32x4 acc[4][4];
#pragma unroll
  for (int i = 0; i < 4; ++i)
#pragma unroll
    for (int j = 0; j < 4; ++j) acc[i][j] = (f32x4){0.f, 0.f, 0.f, 0.f};

#define G2_STAGE_B(bufp, kelem) do { \
    _Pragma("unroll") for (int i = 0; i < 4; ++i) { \
      int sr = w * 32 + i * 8 + lr8; \
      async16(Bt + (size_t)(n0 + sr) * K + (kelem) + cswz, \
              smB + (bufp) * 16384 + (w * 4 + i) * 512); } } while (0)
#define G2_LOAD_A(kelem) do { \
    const float* ap = simf + agbase + (kelem); \
    ra0 = *(const float4*)(ap); ra1 = *(const float4*)(ap + 4); \
    ra2 = *(const float4*)(ap + 8); ra3 = *(const float4*)(ap + 12); } while (0)
#define G2_WRITE_A(bufp) do { \
    short8 lo, hi; \
    lo[0]=f32_to_bf16(__expf(ra0.x)); lo[1]=f32_to_bf16(__expf(ra0.y)); \
    lo[2]=f32_to_bf16(__expf(ra0.z)); lo[3]=f32_to_bf16(__expf(ra0.w)); \
    lo[4]=f32_to_bf16(__expf(ra1.x)); lo[5]=f32_to_bf16(__expf(ra1.y)); \
    lo[6]=f32_to_bf16(__expf(ra1.z)); lo[7]=f32_to_bf16(__expf(ra1.w)); \
    hi[0]=f32_to_bf16(__expf(ra2.x)); hi[1]=f32_to_bf16(__expf(ra2.y)); \
    hi[2]=f32_to_bf16(__expf(ra2.z)); hi[3]=f32_to_bf16(__expf(ra2.w)); \
    hi[4]=f32_to_bf16(__expf(ra3.x)); hi[5]=f32_to_bf16(__expf(ra3.y)); \
    hi[6]=f32_to_bf16(__expf(ra3.z)); hi[7]=f32_to_bf16(__expf(ra3.w)); \
    char* abase = (char*)smA + (bufp) * 16384 + arow * 128; \
    *(short8*)(abase + (acolb ^ asw)) = lo; \
    *(short8*)(abase + ((acolb + 16) ^ asw)) = hi; } while (0)

  float4 ra0, ra1, ra2, ra3;
  // prologue: tile 0
  G2_STAGE_B(0, 0);
  G2_LOAD_A(0);
  G2_WRITE_A(0);
  __syncthreads();

  const int nIter = K / BK;                 // 64
  int cur = 0;
  for (int it = 0; it < nIter; ++it) {
    if (it + 1 < nIter) {
      G2_STAGE_B(cur ^ 1, (it + 1) * BK);
      G2_LOAD_A((it + 1) * BK);
    }
    const int cab = cur * 8192;             // A elems
    const int cbb = cur * 16384;            // B elems
#pragma unroll
    for (int ks = 0; ks < 2; ++ks) {
      short8 af[4], bf[4];
      const int lrow = l & 15;
      const int kb = ks * 64 + ((l >> 4) << 4);
#pragma unroll
      for (int mi = 0; mi < 4; ++mi) {
        int row = wr * 64 + mi * 16 + lrow;
        int addr = row * 128 + (kb ^ ((row & 7) << 4));
        af[mi] = *(const short8*)(smA + cab + (addr >> 1));
      }
#pragma unroll
      for (int ni = 0; ni < 4; ++ni) {
        int row = wc * 64 + ni * 16 + lrow;
        int addr = row * 128 + (kb ^ ((row & 7) << 4));
        bf[ni] = *(const short8*)(smB + cbb + (addr >> 1));
      }
#pragma unroll
      for (int mi = 0; mi < 4; ++mi)
#pragma unroll
        for (int ni = 0; ni < 4; ++ni)
          acc[mi][ni] = __builtin_amdgcn_mfma_f32_16x16x32_bf16(
              bf[ni], af[mi], acc[mi][ni], 0, 0, 0);
    }
    if (it + 1 < nIter) G2_WRITE_A(cur ^ 1);
    __syncthreads();
    cur ^= 1;
  }

  // epilogue: m = lane&15 (+mi*16+wr*64), n = (lane>>4)*4+r (+ni*16+wc*64)
  const int lcol = l & 15;
  const int rgrp = l >> 4;
#pragma unroll
  for (int mi = 0; mi < 4; ++mi) {
    int grow = m0 + wr * 64 + mi * 16 + lcol;
    float s = 1.0f / rowsum[grow];
#pragma unroll
    for (int ni = 0; ni < 4; ++ni) {
      int ncol = n0 + wc * 64 + ni * 16 + rgrp * 4;
      f32x4 v = acc[mi][ni] * s;
      *(f32x4*)(out + (size_t)grow * D_DIM + ncol) = v;
    }
  }
#undef G2_STAGE_B
#undef G2_LOAD_A
#undef G2_WRITE_A
}

// ---- weights (fallback path only) -----------------------------------------
__global__ __launch_bounds__(256) void weights_kernel(const float* __restrict__ sim,
                                                      const float* __restrict__ rowsum,
                                                      u16* __restrict__ wb) {
  size_t i = ((size_t)blockIdx.x * 256 + threadIdx.x) * 8;
  int row = (int)(i >> 12);
  float inv = 1.0f / rowsum[row];
  float4 a = *(const float4*)(sim + i);
  float4 b = *(const float4*)(sim + i + 4);
  u32 w0 = (u32)f32_to_bf16(__expf(a.x) * inv) | ((u32)f32_to_bf16(__expf(a.y) * inv) << 16);
  u32 w1 = (u32)f32_to_bf16(__expf(a.z) * inv) | ((u32)f32_to_bf16(__expf(a.w) * inv) << 16);
  u32 w2 = (u32)f32_to_bf16(__expf(b.x) * inv) | ((u32)f32_to_bf16(__expf(b.y) * inv) << 16);
  u32 w3 = (u32)f32_to_bf16(__expf(b.z) * inv) | ((u32)f32_to_bf16(__expf(b.w) * inv) << 16);
  uint4 o; o.x = w0; o.y = w1; o.z = w2; o.w = w3;
  *(uint4*)(wb + i) = o;
}

extern "C" void kernel_launch(void* const* d_in, const int* in_sizes, int n_in,
                              void* d_out, int out_size, void* d_ws, size_t ws_size,
                              hipStream_t stream) {
  const float* z = (const float*)d_in[0];
  const float* e = (const float*)d_in[1];
  float* out = (float*)d_out;
  float* sim = out;                                   // [8192,4096]
  float* wout = out + (size_t)M_TOK * N_EXP;          // [8192,1024]

  char* ws = (char*)d_ws;
  const size_t MB = (size_t)1 << 20;
  const bool fused = ws_size >= 36 * MB + 96 * 1024;

  if (fused) {
    u16* zb  = (u16*)ws;                              // 16 MiB
    u16* eb  = (u16*)(ws + 16 * MB);                  // 8 MiB
    u16* ebT = (u16*)(ws + 24 * MB);                  // 8 MiB
    float* rs_part = (float*)(ws + 32 * MB);          // 4 MiB (128 x 8192)
    float* z_sq   = (float*)(ws + 36 * MB);
    float* e_sq   = (float*)(ws + 36 * MB + 32768);
    float* rowsum = (float*)(ws + 36 * MB + 49152);

    prep_convert2<<<M_TOK + N_EXP, 256, 0, stream>>>(z, e, zb, eb, z_sq, e_sq);
    transpose_bf16<<<dim3(N_EXP / 64, D_DIM / 64), 256, 0, stream>>>(eb, ebT);

    // GEMM1: sim -> out (plain stores, L3-warm), partial rowsums, NO Wb
    gemm_bt<1><<<(M_TOK / 128) * (N_EXP / 128), 512, 0, stream>>>(
        zb, eb, M_TOK, N_EXP, D_DIM, sim, N_EXP, z_sq, e_sq, rs_part,
        nullptr, nullptr);

    rowsum_reduce<<<M_TOK / 256, 256, 0, stream>>>(rs_part, rowsum);

    // GEMM2: reads sim f32 from L3, fuses exp+bf16 into A-staging
    gemm2_sim<<<(M_TOK / 128) * (D_DIM / 256), 512, 0, stream>>>(
        sim, ebT, wout, rowsum);
  } else {
    // fallback: zb aliases Wb, separate weights pass (round-9 path)
    u16* Wb  = (u16*)ws;                              // 64 MiB
    u16* zb  = (u16*)ws;                              // aliases Wb
    u16* eb  = (u16*)(ws + 64 * MB);                  // 8 MiB
    u16* ebT = (u16*)(ws + 72 * MB);                  // 8 MiB
    float* rs_part = (float*)(ws + 80 * MB);          // 4 MiB
    float* z_sq   = (float*)(ws + 84 * MB);
    float* e_sq   = (float*)(ws + 84 * MB + 32768);
    float* rowsum = (float*)(ws + 84 * MB + 49152);

    prep_convert2<<<M_TOK + N_EXP, 256, 0, stream>>>(z, e, zb, eb, z_sq, e_sq);
    transpose_bf16<<<dim3(N_EXP / 64, D_DIM / 64), 256, 0, stream>>>(eb, ebT);

    gemm_bt<1><<<(M_TOK / 128) * (N_EXP / 128), 512, 0, stream>>>(
        zb, eb, M_TOK, N_EXP, D_DIM, sim, N_EXP, z_sq, e_sq, rs_part,
        nullptr, nullptr);

    rowsum_reduce<<<M_TOK / 256, 256, 0, stream>>>(rs_part, rowsum);

    weights_kernel<<<(M_TOK * (size_t)N_EXP) / (8 * 256), 256, 0, stream>>>(sim, rowsum, Wb);

    gemm_bt<0><<<(M_TOK / 128) * (D_DIM / 128), 512, 0, stream>>>(
        Wb, ebT, M_TOK, D_DIM, N_EXP, wout, D_DIM, nullptr, nullptr, nullptr,
        nullptr, rowsum);
  }
}

// Round 12
// 219.459 us; speedup vs baseline: 1.0211x; 1.0211x over previous
//
#include <hip/hip_runtime.h>
#include <stdint.h>

// GaussianKernelSimilarity: z[8192,1024] f32, expert_keys[4096,1024] f32
// out0 = exp(-max(|z|^2+|e|^2-2 z.e, 0)/2)  [8192,4096]
// out1 = softmax(out0, axis=-1) @ expert_keys [8192,1024]
//
// Round 12: consolidation on the round-9 structure (best: 187.9).
//  - GEMM1 = round 9 exactly (BK=64, 8 waves, XOR swizzle, no atomics,
//    L2 super-tiles, LDS-transpose exp-once epilogue, Wb store) PLUS
//    non-temporal sim stores (sim never re-read; GEMM2 reads Wb).
//  - GEMM2 rebuilt as gemm2b: BM=64/BN=256/BK=32, 256 thr/4 waves, 40KB LDS
//    -> 4 blocks/CU, 512 blocks all co-resident. Halves Wb cache re-reads
//    (8x -> 4x: 512->256 MB). BK=32 rows use 4-slot XOR swizzle
//    (kb ^ ((row&3)<<4)) + pre-swizzled global source (4-way bank aliasing,
//    the minimum for 16B slots in 64B rows; r10's 8-way was the regression).

#define M_TOK 8192
#define N_EXP 4096
#define D_DIM 1024

typedef __attribute__((ext_vector_type(4))) float f32x4;
typedef __attribute__((ext_vector_type(8))) short short8;
typedef __attribute__((ext_vector_type(4))) unsigned short u16x4;
typedef unsigned short u16;
typedef unsigned int u32;

__device__ __forceinline__ u16 f32_to_bf16(float f) {
  u32 u = __builtin_bit_cast(u32, f);
  u += 0x7fff + ((u >> 16) & 1);   // round-to-nearest-even
  return (u16)(u >> 16);
}

__device__ __forceinline__ void async16(const void* g, void* l) {
  __builtin_amdgcn_global_load_lds((__attribute__((address_space(1))) void*)(g),
                                   (__attribute__((address_space(3))) void*)(l),
                                   16, 0, 0);
}

// ---- prep: f32 -> bf16 convert + row |.|^2 for BOTH z and e (one launch) --
__global__ __launch_bounds__(256) void prep_convert2(const float* __restrict__ zsrc,
                                                     const float* __restrict__ esrc,
                                                     u16* __restrict__ zdst,
                                                     u16* __restrict__ edst,
                                                     float* __restrict__ zsq,
                                                     float* __restrict__ esq) {
  int row = blockIdx.x;
  const float* src;
  u16* dst;
  float* sq;
  if (row < M_TOK) {
    src = zsrc + (size_t)row * D_DIM;
    dst = zdst + (size_t)row * D_DIM;
    sq = zsq + row;
  } else {
    int r = row - M_TOK;
    src = esrc + (size_t)r * D_DIM;
    dst = edst + (size_t)r * D_DIM;
    sq = esq + r;
  }
  int t = threadIdx.x;                       // 256 threads, 4 elems each
  const float4 v = ((const float4*)src)[t];
  ushort4 h;
  h.x = f32_to_bf16(v.x); h.y = f32_to_bf16(v.y);
  h.z = f32_to_bf16(v.z); h.w = f32_to_bf16(v.w);
  ((ushort4*)dst)[t] = h;
  float p = v.x * v.x + v.y * v.y + v.z * v.z + v.w * v.w;
#pragma unroll
  for (int off = 1; off < 64; off <<= 1) p += __shfl_xor(p, off, 64);
  __shared__ float partial[4];
  if ((t & 63) == 0) partial[t >> 6] = p;
  __syncthreads();
  if (t == 0) *sq = partial[0] + partial[1] + partial[2] + partial[3];
}

// ---- bf16 transpose: eb[4096][1024] -> ebT[1024][4096] --------------------
__global__ __launch_bounds__(256) void transpose_bf16(const u16* __restrict__ src,
                                                      u16* __restrict__ dst) {
  __shared__ u16 tile[64][65];
  int e0 = blockIdx.x * 64;
  int d0 = blockIdx.y * 64;
  int t = threadIdx.x;
  int lr = t >> 4;
  int lc = (t & 15) * 4;
#pragma unroll
  for (int r8 = 0; r8 < 4; ++r8) {
    int row = lr + r8 * 16;
    ushort4 v = *(const ushort4*)(src + (size_t)(e0 + row) * D_DIM + d0 + lc);
    tile[row][lc + 0] = v.x; tile[row][lc + 1] = v.y;
    tile[row][lc + 2] = v.z; tile[row][lc + 3] = v.w;
  }
  __syncthreads();
#pragma unroll
  for (int r8 = 0; r8 < 4; ++r8) {
    int dl = lr + r8 * 16;
    ushort4 v;
    v.x = tile[lc + 0][dl]; v.y = tile[lc + 1][dl];
    v.z = tile[lc + 2][dl]; v.w = tile[lc + 3][dl];
    *(ushort4*)(dst + (size_t)(d0 + dl) * N_EXP + e0 + lc) = v;
  }
}

// ---- rowsum reduce: rowsum[r] = sum_j rs_part[j][r], j in [0,128) ---------
__global__ __launch_bounds__(256) void rowsum_reduce(const float* __restrict__ part,
                                                     float* __restrict__ rowsum) {
  int r = blockIdx.x * 256 + threadIdx.x;    // 32 blocks x 256 = 8192 rows
  float s = 0.f;
#pragma unroll 8
  for (int j = 0; j < 128; ++j) s += part[(size_t)j * M_TOK + r];
  rowsum[r] = s;
}

// ---- gemm_bt: round-9 GEMM1 (+ EPI=0 fallback GEMM2) ----------------------
// 128x128 tile, BK=64, 512 threads = 8 waves (2M x 4N), dbuf 64 KiB.
// LDS XOR-swizzle on read, pre-swizzled global source for global_load_lds.
// SWAPPED operands mfma(bf, af, acc):
//   m-row = lane&15 (+mi*16+wr*64), n-col = (lane>>4)*4+reg (+ni*16+wc*32)
// EPI=1: XCD stripe + 8m x 4n super-tiles; LDS-transposed full-line sim
//   stores (non-temporal: never re-read); es=exp(sim) once -> Wb + partial
//   rowsum rs_part[slot][row] (no atomics).
// EPI=0: store acc * (1/scale[row]).
template <int EPI>
__global__ __launch_bounds__(512, 4) void gemm_bt(const u16* __restrict__ A,
                                                  const u16* __restrict__ Bt,
                                                  int Mdim, int Ndim, int Kdim,
                                                  float* __restrict__ out, int ldo,
                                                  const float* __restrict__ a_sq,
                                                  const float* __restrict__ b_sq,
                                                  float* __restrict__ rs_part,
                                                  u16* __restrict__ wb,
                                                  const float* __restrict__ scale) {
  constexpr int BM = 128, BN = 128, BK = 64;
  __shared__ __align__(16) u16 smA[2 * BM * BK];   // 32 KiB
  __shared__ __align__(16) u16 smB[2 * BN * BK];   // 32 KiB

  const int wg = blockIdx.x;
  int m0, n0, ntile = 0;
  if (EPI == 1) {
    const int xcd = wg & 7;
    const int idx = wg >> 3;
    const int sup = idx >> 5;
    const int mloc = (idx & 31) >> 2;
    const int nloc = idx & 3;
    m0 = (xcd * 8 + mloc) * BM;
    ntile = sup * 4 + nloc;
    n0 = ntile * BN;
  } else {
    const int nTilesN = Ndim / BN;
    const int nwg = (Mdim / BM) * nTilesN;
    const int cpx = nwg >> 3;
    const int swz = (wg & 7) * cpx + (wg >> 3);
    m0 = (swz / nTilesN) * BM;
    n0 = (swz % nTilesN) * BN;
  }

  const int t = threadIdx.x;
  const int l = t & 63;
  const int w = t >> 6;          // wave 0..7
  const int wr = w >> 2;         // 0..1 (M)
  const int wc = w & 3;          // 0..3 (N)
  const int lr8 = l >> 3;
  const int cswz = (((l & 7) ^ lr8) << 3);
  const int s0 = w * 2, s1 = w * 2 + 1;
  const int str0 = s0 * 8 + lr8, str1 = s1 * 8 + lr8;

  f32x4 acc[4][2];
#pragma unroll
  for (int i = 0; i < 4; ++i)
#pragma unroll
    for (int j = 0; j < 2; ++j) acc[i][j] = (f32x4){0.f, 0.f, 0.f, 0.f};

  const int nIter = Kdim / BK;
  async16(A + (size_t)(m0 + str0) * Kdim + cswz, smA + s0 * 512);
  async16(A + (size_t)(m0 + str1) * Kdim + cswz, smA + s1 * 512);
  async16(Bt + (size_t)(n0 + str0) * Kdim + cswz, smB + s0 * 512);
  async16(Bt + (size_t)(n0 + str1) * Kdim + cswz, smB + s1 * 512);
  __syncthreads();

  int cur = 0;
  for (int it = 0; it < nIter; ++it) {
    if (it + 1 < nIter) {
      const int k0 = (it + 1) * BK;
      const int nb = (cur ^ 1) * 8192;
      async16(A + (size_t)(m0 + str0) * Kdim + k0 + cswz, smA + nb + s0 * 512);
      async16(A + (size_t)(m0 + str1) * Kdim + k0 + cswz, smA + nb + s1 * 512);
      async16(Bt + (size_t)(n0 + str0) * Kdim + k0 + cswz, smB + nb + s0 * 512);
      async16(Bt + (size_t)(n0 + str1) * Kdim + k0 + cswz, smB + nb + s1 * 512);
    }
    const int cbase = cur * 8192;
#pragma unroll
    for (int ks = 0; ks < 2; ++ks) {
      short8 af[4], bf[2];
      const int lrow = l & 15;
      const int kb = ks * 64 + ((l >> 4) << 4);
#pragma unroll
      for (int mi = 0; mi < 4; ++mi) {
        int row = wr * 64 + mi * 16 + lrow;
        int addr = row * 128 + (kb ^ ((row & 7) << 4));
        af[mi] = *(const short8*)(smA + cbase + (addr >> 1));
      }
#pragma unroll
      for (int ni = 0; ni < 2; ++ni) {
        int row = wc * 32 + ni * 16 + lrow;
        int addr = row * 128 + (kb ^ ((row & 7) << 4));
        bf[ni] = *(const short8*)(smB + cbase + (addr >> 1));
      }
#pragma unroll
      for (int mi = 0; mi < 4; ++mi)
#pragma unroll
        for (int ni = 0; ni < 2; ++ni)
          acc[mi][ni] = __builtin_amdgcn_mfma_f32_16x16x32_bf16(
              bf[ni], af[mi], acc[mi][ni], 0, 0, 0);
    }
    __syncthreads();
    cur ^= 1;
  }

  const int lcol = l & 15;
  const int rgrp = l >> 4;
  if (EPI == 1) {
    float* ldsT = ((float*)smA) + w * (16 * 36);   // wave-private scratch
    const int rr = l >> 3;
    const int c4 = (l & 7) * 4;
    const int slot = ntile * 4 + wc;
#pragma unroll
    for (int mi = 0; mi < 4; ++mi) {
      int grow = m0 + wr * 64 + mi * 16 + lcol;
      float zq = a_sq[grow];
#pragma unroll
      for (int ni = 0; ni < 2; ++ni) {
        int ncol = n0 + wc * 32 + ni * 16 + rgrp * 4;
        f32x4 eqv = *(const f32x4*)(b_sq + ncol);
        f32x4 simv;
#pragma unroll
        for (int r = 0; r < 4; ++r) {
          float dist2 = fmaxf(zq + eqv[r] - 2.0f * acc[mi][ni][r], 0.0f);
          simv[r] = __expf(-0.5f * dist2);
        }
        *(f32x4*)(ldsT + lcol * 36 + ni * 16 + rgrp * 4) = simv;
      }
      asm volatile("s_waitcnt lgkmcnt(0)" ::: "memory");
#pragma unroll
      for (int pass = 0; pass < 2; ++pass) {
        int rrow = pass * 8 + rr;
        f32x4 sv = *(const f32x4*)(ldsT + rrow * 36 + c4);
        int growr = m0 + wr * 64 + mi * 16 + rrow;
        size_t gbase = (size_t)growr * ldo + (n0 + wc * 32 + c4);
        __builtin_nontemporal_store(sv, (f32x4*)(out + gbase));  // never re-read
        f32x4 es;
#pragma unroll
        for (int r = 0; r < 4; ++r) es[r] = __expf(sv[r]);
        if (wb) {
          u16x4 wv;
          wv.x = f32_to_bf16(es[0]); wv.y = f32_to_bf16(es[1]);
          wv.z = f32_to_bf16(es[2]); wv.w = f32_to_bf16(es[3]);
          *(u16x4*)(wb + gbase) = wv;                            // cached: re-read
        }
        float p = es[0] + es[1] + es[2] + es[3];
        p += __shfl_xor(p, 1, 64);
        p += __shfl_xor(p, 2, 64);
        p += __shfl_xor(p, 4, 64);
        if ((l & 7) == 0) rs_part[(size_t)slot * M_TOK + growr] = p;
      }
    }
  } else {
#pragma unroll
    for (int mi = 0; mi < 4; ++mi) {
      int grow = m0 + wr * 64 + mi * 16 + lcol;
      float s = scale ? (1.0f / scale[grow]) : 1.0f;
#pragma unroll
      for (int ni = 0; ni < 2; ++ni) {
        int ncol = n0 + wc * 32 + ni * 16 + rgrp * 4;
        f32x4 v = acc[mi][ni] * s;
        *(f32x4*)(out + (size_t)grow * ldo + ncol) = v;
      }
    }
  }
}

// ---- gemm2b: wout = (Wb @ ebT^T) / rowsum ---------------------------------
// BM=64, BN=256, BK=32, 256 threads = 4 waves (wave w owns cols [w*64,w*64+64)).
// LDS 40 KiB (A 8K dbuf + B 32K dbuf) -> 4 blocks/CU; grid 512 = all resident.
// BK=32 rows are 64B: 4-slot XOR swizzle kb^((row&3)<<4) on reads + matching
// pre-swizzled global source col ((l&3)^((l>>2)&3))*8 for global_load_lds.
// SWAPPED operands mfma(bf, af): m-row = lane&15 + mi*16,
// n-col = (lane>>4)*4+reg + ni*16 + w*64.
__global__ __launch_bounds__(256, 4) void gemm2b(const u16* __restrict__ A,   // Wb [8192][4096]
                                                 const u16* __restrict__ Bt,  // ebT [1024][4096]
                                                 float* __restrict__ out,
                                                 const float* __restrict__ rowsum) {
  constexpr int BM = 64, BN = 256, BK = 32;
  constexpr int K = N_EXP;
  __shared__ __align__(16) u16 smA[2 * BM * BK];   // 8 KiB
  __shared__ __align__(16) u16 smB[2 * BN * BK];   // 32 KiB

  const int wg = blockIdx.x;                // 0..511
  const int swz = (wg & 7) * 64 + (wg >> 3);
  const int m0 = (swz >> 2) * BM;           // 128 m-tiles
  const int n0 = (swz & 3) * BN;            // 4 n-tiles

  const int t = threadIdx.x;
  const int l = t & 63;
  const int w = t >> 6;                     // 0..3
  const int lrow = l & 15;
  const int kb16 = (l >> 4) << 4;           // 0/16/32/48 bytes
  const int srow_q = l >> 2;                // 0..15
  const int cswz = (((l & 3) ^ ((l >> 2) & 3)) << 3);   // src col elems

  f32x4 acc[4][4];
#pragma unroll
  for (int i = 0; i < 4; ++i)
#pragma unroll
    for (int j = 0; j < 4; ++j) acc[i][j] = (f32x4){0.f, 0.f, 0.f, 0.f};

#define S2_A(bufp, kelem) \
  async16(A + (size_t)(m0 + w * 16 + srow_q) * K + (kelem) + cswz, \
          smA + (bufp) * 2048 + w * 512)
#define S2_B(bufp, kelem) do { \
    _Pragma("unroll") for (int i = 0; i < 4; ++i) \
      async16(Bt + (size_t)(n0 + i * 64 + w * 16 + srow_q) * K + (kelem) + cswz, \
              smB + (bufp) * 8192 + i * 2048 + w * 512); } while (0)

  const int nIter = K / BK;                 // 128
  S2_A(0, 0);
  S2_B(0, 0);
  __syncthreads();

  int cur = 0;
  for (int it = 0; it < nIter; ++it) {
    if (it + 1 < nIter) {
      S2_A(cur ^ 1, (it + 1) * BK);
      S2_B(cur ^ 1, (it + 1) * BK);
    }
    const u16* ca = smA + cur * 2048;
    const u16* cb = smB + cur * 8192;
    short8 af[4], bf[4];
#pragma unroll
    for (int mi = 0; mi < 4; ++mi) {
      int row = mi * 16 + lrow;
      int addr = row * 64 + (kb16 ^ ((row & 3) << 4));
      af[mi] = *(const short8*)((const char*)ca + addr);
    }
#pragma unroll
    for (int ni = 0; ni < 4; ++ni) {
      int row = w * 64 + ni * 16 + lrow;
      int addr = row * 64 + (kb16 ^ ((row & 3) << 4));
      bf[ni] = *(const short8*)((const char*)cb + addr);
    }
#pragma unroll
    for (int mi = 0; mi < 4; ++mi)
#pragma unroll
      for (int ni = 0; ni < 4; ++ni)
        acc[mi][ni] = __builtin_amdgcn_mfma_f32_16x16x32_bf16(
            bf[ni], af[mi], acc[mi][ni], 0, 0, 0);
    __syncthreads();
    cur ^= 1;
  }

  const int rgrp = l >> 4;
#pragma unroll
  for (int mi = 0; mi < 4; ++mi) {
    int grow = m0 + mi * 16 + lrow;
    float s = 1.0f / rowsum[grow];
#pragma unroll
    for (int ni = 0; ni < 4; ++ni) {
      int ncol = n0 + w * 64 + ni * 16 + rgrp * 4;
      f32x4 v = acc[mi][ni] * s;
      *(f32x4*)(out + (size_t)grow * D_DIM + ncol) = v;
    }
  }
#undef S2_A
#undef S2_B
}

// ---- weights (fallback path only) -----------------------------------------
__global__ __launch_bounds__(256) void weights_kernel(const float* __restrict__ sim,
                                                      const float* __restrict__ rowsum,
                                                      u16* __restrict__ wb) {
  size_t i = ((size_t)blockIdx.x * 256 + threadIdx.x) * 8;
  int row = (int)(i >> 12);
  float inv = 1.0f / rowsum[row];
  float4 a = *(const float4*)(sim + i);
  float4 b = *(const float4*)(sim + i + 4);
  u32 w0 = (u32)f32_to_bf16(__expf(a.x) * inv) | ((u32)f32_to_bf16(__expf(a.y) * inv) << 16);
  u32 w1 = (u32)f32_to_bf16(__expf(a.z) * inv) | ((u32)f32_to_bf16(__expf(a.w) * inv) << 16);
  u32 w2 = (u32)f32_to_bf16(__expf(b.x) * inv) | ((u32)f32_to_bf16(__expf(b.y) * inv) << 16);
  u32 w3 = (u32)f32_to_bf16(__expf(b.z) * inv) | ((u32)f32_to_bf16(__expf(b.w) * inv) << 16);
  uint4 o; o.x = w0; o.y = w1; o.z = w2; o.w = w3;
  *(uint4*)(wb + i) = o;
}

extern "C" void kernel_launch(void* const* d_in, const int* in_sizes, int n_in,
                              void* d_out, int out_size, void* d_ws, size_t ws_size,
                              hipStream_t stream) {
  const float* z = (const float*)d_in[0];
  const float* e = (const float*)d_in[1];
  float* out = (float*)d_out;
  float* sim = out;                                   // [8192,4096]
  float* wout = out + (size_t)M_TOK * N_EXP;          // [8192,1024]

  char* ws = (char*)d_ws;
  const size_t MB = (size_t)1 << 20;
  const bool fused = ws_size >= 100 * MB + 96 * 1024;

  if (fused) {
    u16* zb  = (u16*)ws;                              // 16 MiB
    u16* eb  = (u16*)(ws + 16 * MB);                  // 8 MiB
    u16* ebT = (u16*)(ws + 24 * MB);                  // 8 MiB
    u16* Wb  = (u16*)(ws + 32 * MB);                  // 64 MiB
    float* rs_part = (float*)(ws + 96 * MB);          // 4 MiB (128 x 8192)
    float* z_sq   = (float*)(ws + 100 * MB);
    float* e_sq   = (float*)(ws + 100 * MB + 32768);
    float* rowsum = (float*)(ws + 100 * MB + 49152);

    prep_convert2<<<M_TOK + N_EXP, 256, 0, stream>>>(z, e, zb, eb, z_sq, e_sq);
    transpose_bf16<<<dim3(N_EXP / 64, D_DIM / 64), 256, 0, stream>>>(eb, ebT);

    // GEMM1: sim -> out (nt full-line), bf16(exp(sim)) -> Wb, partial rowsums
    gemm_bt<1><<<(M_TOK / 128) * (N_EXP / 128), 512, 0, stream>>>(
        zb, eb, M_TOK, N_EXP, D_DIM, sim, N_EXP, z_sq, e_sq, rs_part, Wb, nullptr);

    rowsum_reduce<<<M_TOK / 256, 256, 0, stream>>>(rs_part, rowsum);

    // GEMM2: wout = (Wb @ E) / rowsum, 4-blocks/CU shape
    gemm2b<<<(M_TOK / 64) * (D_DIM / 256), 256, 0, stream>>>(Wb, ebT, wout, rowsum);
  } else {
    // fallback: zb aliases Wb, separate weights pass (round-9 path)
    u16* Wb  = (u16*)ws;                              // 64 MiB
    u16* zb  = (u16*)ws;                              // aliases Wb
    u16* eb  = (u16*)(ws + 64 * MB);                  // 8 MiB
    u16* ebT = (u16*)(ws + 72 * MB);                  // 8 MiB
    float* rs_part = (float*)(ws + 80 * MB);          // 4 MiB
    float* z_sq   = (float*)(ws + 84 * MB);
    float* e_sq   = (float*)(ws + 84 * MB + 32768);
    float* rowsum = (float*)(ws + 84 * MB + 49152);

    prep_convert2<<<M_TOK + N_EXP, 256, 0, stream>>>(z, e, zb, eb, z_sq, e_sq);
    transpose_bf16<<<dim3(N_EXP / 64, D_DIM / 64), 256, 0, stream>>>(eb, ebT);

    gemm_bt<1><<<(M_TOK / 128) * (N_EXP / 128), 512, 0, stream>>>(
        zb, eb, M_TOK, N_EXP, D_DIM, sim, N_EXP, z_sq, e_sq, rs_part,
        nullptr, nullptr);

    rowsum_reduce<<<M_TOK / 256, 256, 0, stream>>>(rs_part, rowsum);

    weights_kernel<<<(M_TOK * (size_t)N_EXP) / (8 * 256), 256, 0, stream>>>(sim, rowsum, Wb);

    gemm_bt<0><<<(M_TOK / 128) * (D_DIM / 128), 512, 0, stream>>>(
        Wb, ebT, M_TOK, D_DIM, N_EXP, wout, D_DIM, nullptr, nullptr, nullptr,
        nullptr, rowsum);
  }
}

// Round 13
// 200.852 us; speedup vs baseline: 1.1157x; 1.0926x over previous
//
#include <hip/hip_runtime.h>
#include <stdint.h>

// GaussianKernelSimilarity: z[8192,1024] f32, expert_keys[4096,1024] f32
// out0 = exp(-max(|z|^2+|e|^2-2 z.e, 0)/2)  [8192,4096]
// out1 = softmax(out0, axis=-1) @ expert_keys [8192,1024]
//
// Round 13: recomposition from measured parts (no new GEMM structures).
//  - GEMM1 = r9 K-loop with a LEAN epilogue: sim only (LDS-transpose,
//    full-line plain f32x4 stores). No Wb, no exp-for-rowsum, no rs_part.
//    (r11 measured this variant at ~83 us vs 110 with the fat epilogue.)
//  - espass (new): elementwise pass over sim (L3-warm): Wb = bf16(exp(sim))
//    (unnormalized -> independent of rowsum) + block row-reduction ->
//    rowsum[row] directly. Replaces GEMM1's fat epilogue + rowsum_reduce.
//    ~192 MB traffic ~= 31 us.
//  - GEMM2 = r9's gemm_bt<0> exactly (~50 us measured).

#define M_TOK 8192
#define N_EXP 4096
#define D_DIM 1024

typedef __attribute__((ext_vector_type(4))) float f32x4;
typedef __attribute__((ext_vector_type(8))) short short8;
typedef unsigned short u16;
typedef unsigned int u32;

__device__ __forceinline__ u16 f32_to_bf16(float f) {
  u32 u = __builtin_bit_cast(u32, f);
  u += 0x7fff + ((u >> 16) & 1);   // round-to-nearest-even
  return (u16)(u >> 16);
}

__device__ __forceinline__ void async16(const void* g, void* l) {
  __builtin_amdgcn_global_load_lds((__attribute__((address_space(1))) void*)(g),
                                   (__attribute__((address_space(3))) void*)(l),
                                   16, 0, 0);
}

// ---- prep: f32 -> bf16 convert + row |.|^2 for BOTH z and e (one launch) --
__global__ __launch_bounds__(256) void prep_convert2(const float* __restrict__ zsrc,
                                                     const float* __restrict__ esrc,
                                                     u16* __restrict__ zdst,
                                                     u16* __restrict__ edst,
                                                     float* __restrict__ zsq,
                                                     float* __restrict__ esq) {
  int row = blockIdx.x;
  const float* src;
  u16* dst;
  float* sq;
  if (row < M_TOK) {
    src = zsrc + (size_t)row * D_DIM;
    dst = zdst + (size_t)row * D_DIM;
    sq = zsq + row;
  } else {
    int r = row - M_TOK;
    src = esrc + (size_t)r * D_DIM;
    dst = edst + (size_t)r * D_DIM;
    sq = esq + r;
  }
  int t = threadIdx.x;                       // 256 threads, 4 elems each
  const float4 v = ((const float4*)src)[t];
  ushort4 h;
  h.x = f32_to_bf16(v.x); h.y = f32_to_bf16(v.y);
  h.z = f32_to_bf16(v.z); h.w = f32_to_bf16(v.w);
  ((ushort4*)dst)[t] = h;
  float p = v.x * v.x + v.y * v.y + v.z * v.z + v.w * v.w;
#pragma unroll
  for (int off = 1; off < 64; off <<= 1) p += __shfl_xor(p, off, 64);
  __shared__ float partial[4];
  if ((t & 63) == 0) partial[t >> 6] = p;
  __syncthreads();
  if (t == 0) *sq = partial[0] + partial[1] + partial[2] + partial[3];
}

// ---- bf16 transpose: eb[4096][1024] -> ebT[1024][4096] --------------------
__global__ __launch_bounds__(256) void transpose_bf16(const u16* __restrict__ src,
                                                      u16* __restrict__ dst) {
  __shared__ u16 tile[64][65];
  int e0 = blockIdx.x * 64;
  int d0 = blockIdx.y * 64;
  int t = threadIdx.x;
  int lr = t >> 4;
  int lc = (t & 15) * 4;
#pragma unroll
  for (int r8 = 0; r8 < 4; ++r8) {
    int row = lr + r8 * 16;
    ushort4 v = *(const ushort4*)(src + (size_t)(e0 + row) * D_DIM + d0 + lc);
    tile[row][lc + 0] = v.x; tile[row][lc + 1] = v.y;
    tile[row][lc + 2] = v.z; tile[row][lc + 3] = v.w;
  }
  __syncthreads();
#pragma unroll
  for (int r8 = 0; r8 < 4; ++r8) {
    int dl = lr + r8 * 16;
    ushort4 v;
    v.x = tile[lc + 0][dl]; v.y = tile[lc + 1][dl];
    v.z = tile[lc + 2][dl]; v.w = tile[lc + 3][dl];
    *(ushort4*)(dst + (size_t)(d0 + dl) * N_EXP + e0 + lc) = v;
  }
}

// ---- espass: Wb = bf16(exp(sim)); rowsum[row] = sum(exp(sim[row,:])) ------
// One block per row: 256 threads x 16 f32. sim is L3-warm (just written).
__global__ __launch_bounds__(256) void espass(const float* __restrict__ sim,
                                              u16* __restrict__ wb,
                                              float* __restrict__ rowsum) {
  const int row = blockIdx.x;
  const float* sp = sim + (size_t)row * N_EXP;
  u16* wp = wb + (size_t)row * N_EXP;
  const int t = threadIdx.x;
  const int base = t * 16;
  f32x4 v0 = *(const f32x4*)(sp + base);
  f32x4 v1 = *(const f32x4*)(sp + base + 4);
  f32x4 v2 = *(const f32x4*)(sp + base + 8);
  f32x4 v3 = *(const f32x4*)(sp + base + 12);
  f32x4 e0, e1, e2, e3;
#pragma unroll
  for (int r = 0; r < 4; ++r) {
    e0[r] = __expf(v0[r]); e1[r] = __expf(v1[r]);
    e2[r] = __expf(v2[r]); e3[r] = __expf(v3[r]);
  }
  short8 lo, hi;
#pragma unroll
  for (int r = 0; r < 4; ++r) {
    lo[r]     = (short)f32_to_bf16(e0[r]);
    lo[r + 4] = (short)f32_to_bf16(e1[r]);
    hi[r]     = (short)f32_to_bf16(e2[r]);
    hi[r + 4] = (short)f32_to_bf16(e3[r]);
  }
  *(short8*)(wp + base) = lo;
  *(short8*)(wp + base + 8) = hi;
  float p = (e0[0] + e0[1] + e0[2] + e0[3]) + (e1[0] + e1[1] + e1[2] + e1[3]) +
            (e2[0] + e2[1] + e2[2] + e2[3]) + (e3[0] + e3[1] + e3[2] + e3[3]);
#pragma unroll
  for (int off = 1; off < 64; off <<= 1) p += __shfl_xor(p, off, 64);
  __shared__ float partial[4];
  if ((t & 63) == 0) partial[t >> 6] = p;
  __syncthreads();
  if (t == 0) rowsum[row] = partial[0] + partial[1] + partial[2] + partial[3];
}

// ---- gemm_bt: r9 K-loop. EPI=1 lean sim epilogue; EPI=0 scaled store ------
// 128x128 tile, BK=64, 512 threads = 8 waves (2M x 4N), dbuf 64 KiB.
// LDS XOR-swizzle on read, pre-swizzled global source for global_load_lds.
// SWAPPED operands mfma(bf, af, acc):
//   m-row = lane&15 (+mi*16+wr*64), n-col = (lane>>4)*4+reg (+ni*16+wc*32)
// EPI=1: XCD stripe + 8m x 4n super-tiles; sim=exp(-d2/2) staged through
//   wave-private LDS -> transposed full-line PLAIN f32x4 stores (L3-warm for
//   espass). Nothing else.
// EPI=0: XCD chunk swizzle; store acc * (1/scale[row]).
template <int EPI>
__global__ __launch_bounds__(512, 4) void gemm_bt(const u16* __restrict__ A,
                                                  const u16* __restrict__ Bt,
                                                  int Mdim, int Ndim, int Kdim,
                                                  float* __restrict__ out, int ldo,
                                                  const float* __restrict__ a_sq,
                                                  const float* __restrict__ b_sq,
                                                  const float* __restrict__ scale) {
  constexpr int BM = 128, BN = 128, BK = 64;
  __shared__ __align__(16) u16 smA[2 * BM * BK];   // 32 KiB
  __shared__ __align__(16) u16 smB[2 * BN * BK];   // 32 KiB

  const int wg = blockIdx.x;
  int m0, n0;
  if (EPI == 1) {
    const int xcd = wg & 7;
    const int idx = wg >> 3;
    const int sup = idx >> 5;
    const int mloc = (idx & 31) >> 2;
    const int nloc = idx & 3;
    m0 = (xcd * 8 + mloc) * BM;
    n0 = (sup * 4 + nloc) * BN;
  } else {
    const int nTilesN = Ndim / BN;
    const int nwg = (Mdim / BM) * nTilesN;
    const int cpx = nwg >> 3;
    const int swz = (wg & 7) * cpx + (wg >> 3);
    m0 = (swz / nTilesN) * BM;
    n0 = (swz % nTilesN) * BN;
  }

  const int t = threadIdx.x;
  const int l = t & 63;
  const int w = t >> 6;          // wave 0..7
  const int wr = w >> 2;         // 0..1 (M)
  const int wc = w & 3;          // 0..3 (N)
  const int lr8 = l >> 3;
  const int cswz = (((l & 7) ^ lr8) << 3);
  const int s0 = w * 2, s1 = w * 2 + 1;
  const int str0 = s0 * 8 + lr8, str1 = s1 * 8 + lr8;

  f32x4 acc[4][2];
#pragma unroll
  for (int i = 0; i < 4; ++i)
#pragma unroll
    for (int j = 0; j < 2; ++j) acc[i][j] = (f32x4){0.f, 0.f, 0.f, 0.f};

  const int nIter = Kdim / BK;
  async16(A + (size_t)(m0 + str0) * Kdim + cswz, smA + s0 * 512);
  async16(A + (size_t)(m0 + str1) * Kdim + cswz, smA + s1 * 512);
  async16(Bt + (size_t)(n0 + str0) * Kdim + cswz, smB + s0 * 512);
  async16(Bt + (size_t)(n0 + str1) * Kdim + cswz, smB + s1 * 512);
  __syncthreads();

  int cur = 0;
  for (int it = 0; it < nIter; ++it) {
    if (it + 1 < nIter) {
      const int k0 = (it + 1) * BK;
      const int nb = (cur ^ 1) * 8192;
      async16(A + (size_t)(m0 + str0) * Kdim + k0 + cswz, smA + nb + s0 * 512);
      async16(A + (size_t)(m0 + str1) * Kdim + k0 + cswz, smA + nb + s1 * 512);
      async16(Bt + (size_t)(n0 + str0) * Kdim + k0 + cswz, smB + nb + s0 * 512);
      async16(Bt + (size_t)(n0 + str1) * Kdim + k0 + cswz, smB + nb + s1 * 512);
    }
    const int cbase = cur * 8192;
#pragma unroll
    for (int ks = 0; ks < 2; ++ks) {
      short8 af[4], bf[2];
      const int lrow = l & 15;
      const int kb = ks * 64 + ((l >> 4) << 4);
#pragma unroll
      for (int mi = 0; mi < 4; ++mi) {
        int row = wr * 64 + mi * 16 + lrow;
        int addr = row * 128 + (kb ^ ((row & 7) << 4));
        af[mi] = *(const short8*)(smA + cbase + (addr >> 1));
      }
#pragma unroll
      for (int ni = 0; ni < 2; ++ni) {
        int row = wc * 32 + ni * 16 + lrow;
        int addr = row * 128 + (kb ^ ((row & 7) << 4));
        bf[ni] = *(const short8*)(smB + cbase + (addr >> 1));
      }
#pragma unroll
      for (int mi = 0; mi < 4; ++mi)
#pragma unroll
        for (int ni = 0; ni < 2; ++ni)
          acc[mi][ni] = __builtin_amdgcn_mfma_f32_16x16x32_bf16(
              bf[ni], af[mi], acc[mi][ni], 0, 0, 0);
    }
    __syncthreads();
    cur ^= 1;
  }

  const int lcol = l & 15;
  const int rgrp = l >> 4;
  if (EPI == 1) {
    // lean epilogue: sim only, LDS-transposed full-line plain stores
    float* ldsT = ((float*)smA) + w * (16 * 36);   // wave-private scratch
    const int rr = l >> 3;
    const int c4 = (l & 7) * 4;
#pragma unroll
    for (int mi = 0; mi < 4; ++mi) {
      int grow = m0 + wr * 64 + mi * 16 + lcol;
      float zq = a_sq[grow];
#pragma unroll
      for (int ni = 0; ni < 2; ++ni) {
        int ncol = n0 + wc * 32 + ni * 16 + rgrp * 4;
        f32x4 eqv = *(const f32x4*)(b_sq + ncol);
        f32x4 simv;
#pragma unroll
        for (int r = 0; r < 4; ++r) {
          float dist2 = fmaxf(zq + eqv[r] - 2.0f * acc[mi][ni][r], 0.0f);
          simv[r] = __expf(-0.5f * dist2);
        }
        *(f32x4*)(ldsT + lcol * 36 + ni * 16 + rgrp * 4) = simv;
      }
      asm volatile("s_waitcnt lgkmcnt(0)" ::: "memory");
#pragma unroll
      for (int pass = 0; pass < 2; ++pass) {
        int rrow = pass * 8 + rr;
        f32x4 sv = *(const f32x4*)(ldsT + rrow * 36 + c4);
        int growr = m0 + wr * 64 + mi * 16 + rrow;
        size_t gbase = (size_t)growr * ldo + (n0 + wc * 32 + c4);
        *(f32x4*)(out + gbase) = sv;    // plain: L3-warm for espass
      }
    }
  } else {
#pragma unroll
    for (int mi = 0; mi < 4; ++mi) {
      int grow = m0 + wr * 64 + mi * 16 + lcol;
      float s = scale ? (1.0f / scale[grow]) : 1.0f;
#pragma unroll
      for (int ni = 0; ni < 2; ++ni) {
        int ncol = n0 + wc * 32 + ni * 16 + rgrp * 4;
        f32x4 v = acc[mi][ni] * s;
        *(f32x4*)(out + (size_t)grow * ldo + ncol) = v;
      }
    }
  }
}

extern "C" void kernel_launch(void* const* d_in, const int* in_sizes, int n_in,
                              void* d_out, int out_size, void* d_ws, size_t ws_size,
                              hipStream_t stream) {
  const float* z = (const float*)d_in[0];
  const float* e = (const float*)d_in[1];
  float* out = (float*)d_out;
  float* sim = out;                                   // [8192,4096]
  float* wout = out + (size_t)M_TOK * N_EXP;          // [8192,1024]

  char* ws = (char*)d_ws;
  const size_t MB = (size_t)1 << 20;

  u16 *zb, *eb, *ebT, *Wb;
  float *z_sq, *e_sq, *rowsum;
  if (ws_size >= 96 * MB + 80 * 1024) {
    zb  = (u16*)ws;                              // 16 MiB
    eb  = (u16*)(ws + 16 * MB);                  // 8 MiB
    ebT = (u16*)(ws + 24 * MB);                  // 8 MiB
    Wb  = (u16*)(ws + 32 * MB);                  // 64 MiB
    z_sq   = (float*)(ws + 96 * MB);
    e_sq   = (float*)(ws + 96 * MB + 32768);
    rowsum = (float*)(ws + 96 * MB + 49152);
  } else {
    // aliased layout (needs 80 MiB + 80 KiB): zb aliases Wb. Safe: zb is
    // consumed only by GEMM1, which completes before espass writes Wb.
    Wb  = (u16*)ws;                              // 64 MiB
    zb  = (u16*)ws;                              // aliases Wb
    eb  = (u16*)(ws + 64 * MB);                  // 8 MiB
    ebT = (u16*)(ws + 72 * MB);                  // 8 MiB
    z_sq   = (float*)(ws + 80 * MB);
    e_sq   = (float*)(ws + 80 * MB + 32768);
    rowsum = (float*)(ws + 80 * MB + 49152);
  }

  prep_convert2<<<M_TOK + N_EXP, 256, 0, stream>>>(z, e, zb, eb, z_sq, e_sq);
  transpose_bf16<<<dim3(N_EXP / 64, D_DIM / 64), 256, 0, stream>>>(eb, ebT);

  // GEMM1 (lean): sim -> out (plain full-line stores)
  gemm_bt<1><<<(M_TOK / 128) * (N_EXP / 128), 512, 0, stream>>>(
      zb, eb, M_TOK, N_EXP, D_DIM, sim, N_EXP, z_sq, e_sq, nullptr);

  // espass: Wb = bf16(exp(sim)) (unnormalized), rowsum = row sums of exp(sim)
  espass<<<M_TOK, 256, 0, stream>>>(sim, Wb, rowsum);

  // GEMM2: wout = (Wb @ E) / rowsum[row]
  gemm_bt<0><<<(M_TOK / 128) * (D_DIM / 128), 512, 0, stream>>>(
      Wb, ebT, M_TOK, D_DIM, N_EXP, wout, D_DIM, nullptr, nullptr, rowsum);
}

// Round 14
// 188.303 us; speedup vs baseline: 1.1901x; 1.0666x over previous
//
#include <hip/hip_runtime.h>
#include <stdint.h>

// GaussianKernelSimilarity: z[8192,1024] f32, expert_keys[4096,1024] f32
// out0 = exp(-max(|z|^2+|e|^2-2 z.e, 0)/2)  [8192,4096]
// out1 = softmax(out0, axis=-1) @ expert_keys [8192,1024]
//
// Round 14: round-9 structure (best measured: 187.9) with one cut:
// rowsum_reduce folded into GEMM2's prologue. Each GEMM2 block reduces the
// 128 rowsum partials for its 128 rows into LDS (inv_rs[128]) while its
// first staging loads are in flight; epilogue reads inv_rs instead of a
// precomputed rowsum. Removes one kernel + dependency gap.
// Everything else = round 9 exactly (GEMM1: BK=64, 8 waves, XOR swizzle,
// L2 super-tiles, no atomics, LDS-transpose exp-once epilogue, nt sim
// stores, Wb store; GEMM2: same K-loop, K=4096).

#define M_TOK 8192
#define N_EXP 4096
#define D_DIM 1024

typedef __attribute__((ext_vector_type(4))) float f32x4;
typedef __attribute__((ext_vector_type(8))) short short8;
typedef __attribute__((ext_vector_type(4))) unsigned short u16x4;
typedef unsigned short u16;
typedef unsigned int u32;

__device__ __forceinline__ u16 f32_to_bf16(float f) {
  u32 u = __builtin_bit_cast(u32, f);
  u += 0x7fff + ((u >> 16) & 1);   // round-to-nearest-even
  return (u16)(u >> 16);
}

__device__ __forceinline__ void async16(const void* g, void* l) {
  __builtin_amdgcn_global_load_lds((__attribute__((address_space(1))) void*)(g),
                                   (__attribute__((address_space(3))) void*)(l),
                                   16, 0, 0);
}

// ---- prep: f32 -> bf16 convert + row |.|^2 for BOTH z and e (one launch) --
__global__ __launch_bounds__(256) void prep_convert2(const float* __restrict__ zsrc,
                                                     const float* __restrict__ esrc,
                                                     u16* __restrict__ zdst,
                                                     u16* __restrict__ edst,
                                                     float* __restrict__ zsq,
                                                     float* __restrict__ esq) {
  int row = blockIdx.x;
  const float* src;
  u16* dst;
  float* sq;
  if (row < M_TOK) {
    src = zsrc + (size_t)row * D_DIM;
    dst = zdst + (size_t)row * D_DIM;
    sq = zsq + row;
  } else {
    int r = row - M_TOK;
    src = esrc + (size_t)r * D_DIM;
    dst = edst + (size_t)r * D_DIM;
    sq = esq + r;
  }
  int t = threadIdx.x;                       // 256 threads, 4 elems each
  const float4 v = ((const float4*)src)[t];
  ushort4 h;
  h.x = f32_to_bf16(v.x); h.y = f32_to_bf16(v.y);
  h.z = f32_to_bf16(v.z); h.w = f32_to_bf16(v.w);
  ((ushort4*)dst)[t] = h;
  float p = v.x * v.x + v.y * v.y + v.z * v.z + v.w * v.w;
#pragma unroll
  for (int off = 1; off < 64; off <<= 1) p += __shfl_xor(p, off, 64);
  __shared__ float partial[4];
  if ((t & 63) == 0) partial[t >> 6] = p;
  __syncthreads();
  if (t == 0) *sq = partial[0] + partial[1] + partial[2] + partial[3];
}

// ---- bf16 transpose: eb[4096][1024] -> ebT[1024][4096] --------------------
__global__ __launch_bounds__(256) void transpose_bf16(const u16* __restrict__ src,
                                                      u16* __restrict__ dst) {
  __shared__ u16 tile[64][65];
  int e0 = blockIdx.x * 64;
  int d0 = blockIdx.y * 64;
  int t = threadIdx.x;
  int lr = t >> 4;
  int lc = (t & 15) * 4;
#pragma unroll
  for (int r8 = 0; r8 < 4; ++r8) {
    int row = lr + r8 * 16;
    ushort4 v = *(const ushort4*)(src + (size_t)(e0 + row) * D_DIM + d0 + lc);
    tile[row][lc + 0] = v.x; tile[row][lc + 1] = v.y;
    tile[row][lc + 2] = v.z; tile[row][lc + 3] = v.w;
  }
  __syncthreads();
#pragma unroll
  for (int r8 = 0; r8 < 4; ++r8) {
    int dl = lr + r8 * 16;
    ushort4 v;
    v.x = tile[lc + 0][dl]; v.y = tile[lc + 1][dl];
    v.z = tile[lc + 2][dl]; v.w = tile[lc + 3][dl];
    *(ushort4*)(dst + (size_t)(d0 + dl) * N_EXP + e0 + lc) = v;
  }
}

// ---- rowsum reduce (fallback path only) -----------------------------------
__global__ __launch_bounds__(256) void rowsum_reduce(const float* __restrict__ part,
                                                     float* __restrict__ rowsum) {
  int r = blockIdx.x * 256 + threadIdx.x;
  float s = 0.f;
#pragma unroll 8
  for (int j = 0; j < 128; ++j) s += part[(size_t)j * M_TOK + r];
  rowsum[r] = s;
}

// ---- gemm_bt: round-9 kernel + integrated rowsum reduce in EPI=0 ----------
// 128x128 tile, BK=64, 512 threads = 8 waves (2M x 4N), dbuf 64 KiB.
// LDS XOR-swizzle on read, pre-swizzled global source for global_load_lds.
// SWAPPED operands mfma(bf, af, acc):
//   m-row = lane&15 (+mi*16+wr*64), n-col = (lane>>4)*4+reg (+ni*16+wc*32)
// EPI=1: XCD stripe + 8m x 4n super-tiles; LDS-transposed full-line sim
//   stores (nt); es=exp(sim) once -> Wb + partial rowsum rs_part[slot][row].
// EPI=0: XCD chunk swizzle; if rs_part non-null: cooperative 128-partial
//   reduce into inv_rs[] LDS during prologue (hides under staging latency),
//   epilogue scales by inv_rs; else scales by 1/scale[row] (or 1).
template <int EPI>
__global__ __launch_bounds__(512, 4) void gemm_bt(const u16* __restrict__ A,
                                                  const u16* __restrict__ Bt,
                                                  int Mdim, int Ndim, int Kdim,
                                                  float* __restrict__ out, int ldo,
                                                  const float* __restrict__ a_sq,
                                                  const float* __restrict__ b_sq,
                                                  float* __restrict__ rs_part,
                                                  u16* __restrict__ wb,
                                                  const float* __restrict__ scale) {
  constexpr int BM = 128, BN = 128, BK = 64;
  __shared__ __align__(16) u16 smA[2 * BM * BK];   // 32 KiB
  __shared__ __align__(16) u16 smB[2 * BN * BK];   // 32 KiB
  __shared__ float inv_rs[BM];                     // 512 B (EPI=0 integrated)

  const int wg = blockIdx.x;
  int m0, n0, ntile = 0;
  if (EPI == 1) {
    const int xcd = wg & 7;
    const int idx = wg >> 3;
    const int sup = idx >> 5;
    const int mloc = (idx & 31) >> 2;
    const int nloc = idx & 3;
    m0 = (xcd * 8 + mloc) * BM;
    ntile = sup * 4 + nloc;
    n0 = ntile * BN;
  } else {
    const int nTilesN = Ndim / BN;
    const int nwg = (Mdim / BM) * nTilesN;
    const int cpx = nwg >> 3;
    const int swz = (wg & 7) * cpx + (wg >> 3);
    m0 = (swz / nTilesN) * BM;
    n0 = (swz % nTilesN) * BN;
  }

  const int t = threadIdx.x;
  const int l = t & 63;
  const int w = t >> 6;          // wave 0..7
  const int wr = w >> 2;         // 0..1 (M)
  const int wc = w & 3;          // 0..3 (N)
  const int lr8 = l >> 3;
  const int cswz = (((l & 7) ^ lr8) << 3);
  const int s0 = w * 2, s1 = w * 2 + 1;
  const int str0 = s0 * 8 + lr8, str1 = s1 * 8 + lr8;

  f32x4 acc[4][2];
#pragma unroll
  for (int i = 0; i < 4; ++i)
#pragma unroll
    for (int j = 0; j < 2; ++j) acc[i][j] = (f32x4){0.f, 0.f, 0.f, 0.f};

  const int nIter = Kdim / BK;
  async16(A + (size_t)(m0 + str0) * Kdim + cswz, smA + s0 * 512);
  async16(A + (size_t)(m0 + str1) * Kdim + cswz, smA + s1 * 512);
  async16(Bt + (size_t)(n0 + str0) * Kdim + cswz, smB + s0 * 512);
  async16(Bt + (size_t)(n0 + str1) * Kdim + cswz, smB + s1 * 512);

  if (EPI == 0 && rs_part != nullptr) {
    // integrated rowsum reduce for this block's 128 rows, hidden under the
    // prologue staging latency. 4 threads per row, 32 partials each.
    const int rrow = t >> 2;          // 0..127
    const int q = t & 3;              // partial quarter
    float s = 0.f;
#pragma unroll 8
    for (int j = q * 32; j < q * 32 + 32; ++j)
      s += rs_part[(size_t)j * M_TOK + m0 + rrow];
    s += __shfl_xor(s, 1, 64);
    s += __shfl_xor(s, 2, 64);
    if (q == 0) inv_rs[rrow] = 1.0f / s;
  }
  __syncthreads();

  int cur = 0;
  for (int it = 0; it < nIter; ++it) {
    if (it + 1 < nIter) {
      const int k0 = (it + 1) * BK;
      const int nb = (cur ^ 1) * 8192;
      async16(A + (size_t)(m0 + str0) * Kdim + k0 + cswz, smA + nb + s0 * 512);
      async16(A + (size_t)(m0 + str1) * Kdim + k0 + cswz, smA + nb + s1 * 512);
      async16(Bt + (size_t)(n0 + str0) * Kdim + k0 + cswz, smB + nb + s0 * 512);
      async16(Bt + (size_t)(n0 + str1) * Kdim + k0 + cswz, smB + nb + s1 * 512);
    }
    const int cbase = cur * 8192;
#pragma unroll
    for (int ks = 0; ks < 2; ++ks) {
      short8 af[4], bf[2];
      const int lrow = l & 15;
      const int kb = ks * 64 + ((l >> 4) << 4);
#pragma unroll
      for (int mi = 0; mi < 4; ++mi) {
        int row = wr * 64 + mi * 16 + lrow;
        int addr = row * 128 + (kb ^ ((row & 7) << 4));
        af[mi] = *(const short8*)(smA + cbase + (addr >> 1));
      }
#pragma unroll
      for (int ni = 0; ni < 2; ++ni) {
        int row = wc * 32 + ni * 16 + lrow;
        int addr = row * 128 + (kb ^ ((row & 7) << 4));
        bf[ni] = *(const short8*)(smB + cbase + (addr >> 1));
      }
#pragma unroll
      for (int mi = 0; mi < 4; ++mi)
#pragma unroll
        for (int ni = 0; ni < 2; ++ni)
          acc[mi][ni] = __builtin_amdgcn_mfma_f32_16x16x32_bf16(
              bf[ni], af[mi], acc[mi][ni], 0, 0, 0);
    }
    __syncthreads();
    cur ^= 1;
  }

  const int lcol = l & 15;
  const int rgrp = l >> 4;
  if (EPI == 1) {
    float* ldsT = ((float*)smA) + w * (16 * 36);   // wave-private scratch
    const int rr = l >> 3;
    const int c4 = (l & 7) * 4;
    const int slot = ntile * 4 + wc;
#pragma unroll
    for (int mi = 0; mi < 4; ++mi) {
      int grow = m0 + wr * 64 + mi * 16 + lcol;
      float zq = a_sq[grow];
#pragma unroll
      for (int ni = 0; ni < 2; ++ni) {
        int ncol = n0 + wc * 32 + ni * 16 + rgrp * 4;
        f32x4 eqv = *(const f32x4*)(b_sq + ncol);
        f32x4 simv;
#pragma unroll
        for (int r = 0; r < 4; ++r) {
          float dist2 = fmaxf(zq + eqv[r] - 2.0f * acc[mi][ni][r], 0.0f);
          simv[r] = __expf(-0.5f * dist2);
        }
        *(f32x4*)(ldsT + lcol * 36 + ni * 16 + rgrp * 4) = simv;
      }
      asm volatile("s_waitcnt lgkmcnt(0)" ::: "memory");
#pragma unroll
      for (int pass = 0; pass < 2; ++pass) {
        int rrow = pass * 8 + rr;
        f32x4 sv = *(const f32x4*)(ldsT + rrow * 36 + c4);
        int growr = m0 + wr * 64 + mi * 16 + rrow;
        size_t gbase = (size_t)growr * ldo + (n0 + wc * 32 + c4);
        __builtin_nontemporal_store(sv, (f32x4*)(out + gbase));
        f32x4 es;
#pragma unroll
        for (int r = 0; r < 4; ++r) es[r] = __expf(sv[r]);
        if (wb) {
          u16x4 wv;
          wv.x = f32_to_bf16(es[0]); wv.y = f32_to_bf16(es[1]);
          wv.z = f32_to_bf16(es[2]); wv.w = f32_to_bf16(es[3]);
          *(u16x4*)(wb + gbase) = wv;
        }
        float p = es[0] + es[1] + es[2] + es[3];
        p += __shfl_xor(p, 1, 64);
        p += __shfl_xor(p, 2, 64);
        p += __shfl_xor(p, 4, 64);
        if ((l & 7) == 0) rs_part[(size_t)slot * M_TOK + growr] = p;
      }
    }
  } else {
#pragma unroll
    for (int mi = 0; mi < 4; ++mi) {
      int grow = m0 + wr * 64 + mi * 16 + lcol;
      float s;
      if (rs_part != nullptr)      s = inv_rs[wr * 64 + mi * 16 + lcol];
      else if (scale != nullptr)   s = 1.0f / scale[grow];
      else                         s = 1.0f;
#pragma unroll
      for (int ni = 0; ni < 2; ++ni) {
        int ncol = n0 + wc * 32 + ni * 16 + rgrp * 4;
        f32x4 v = acc[mi][ni] * s;
        *(f32x4*)(out + (size_t)grow * ldo + ncol) = v;
      }
    }
  }
}

// ---- weights (fallback path only) -----------------------------------------
__global__ __launch_bounds__(256) void weights_kernel(const float* __restrict__ sim,
                                                      const float* __restrict__ rowsum,
                                                      u16* __restrict__ wb) {
  size_t i = ((size_t)blockIdx.x * 256 + threadIdx.x) * 8;
  int row = (int)(i >> 12);
  float inv = 1.0f / rowsum[row];
  float4 a = *(const float4*)(sim + i);
  float4 b = *(const float4*)(sim + i + 4);
  u32 w0 = (u32)f32_to_bf16(__expf(a.x) * inv) | ((u32)f32_to_bf16(__expf(a.y) * inv) << 16);
  u32 w1 = (u32)f32_to_bf16(__expf(a.z) * inv) | ((u32)f32_to_bf16(__expf(a.w) * inv) << 16);
  u32 w2 = (u32)f32_to_bf16(__expf(b.x) * inv) | ((u32)f32_to_bf16(__expf(b.y) * inv) << 16);
  u32 w3 = (u32)f32_to_bf16(__expf(b.z) * inv) | ((u32)f32_to_bf16(__expf(b.w) * inv) << 16);
  uint4 o; o.x = w0; o.y = w1; o.z = w2; o.w = w3;
  *(uint4*)(wb + i) = o;
}

extern "C" void kernel_launch(void* const* d_in, const int* in_sizes, int n_in,
                              void* d_out, int out_size, void* d_ws, size_t ws_size,
                              hipStream_t stream) {
  const float* z = (const float*)d_in[0];
  const float* e = (const float*)d_in[1];
  float* out = (float*)d_out;
  float* sim = out;                                   // [8192,4096]
  float* wout = out + (size_t)M_TOK * N_EXP;          // [8192,1024]

  char* ws = (char*)d_ws;
  const size_t MB = (size_t)1 << 20;
  const bool fused = ws_size >= 100 * MB + 96 * 1024;

  if (fused) {
    u16* zb  = (u16*)ws;                              // 16 MiB
    u16* eb  = (u16*)(ws + 16 * MB);                  // 8 MiB
    u16* ebT = (u16*)(ws + 24 * MB);                  // 8 MiB
    u16* Wb  = (u16*)(ws + 32 * MB);                  // 64 MiB
    float* rs_part = (float*)(ws + 96 * MB);          // 4 MiB (128 x 8192)
    float* z_sq   = (float*)(ws + 100 * MB);
    float* e_sq   = (float*)(ws + 100 * MB + 32768);

    prep_convert2<<<M_TOK + N_EXP, 256, 0, stream>>>(z, e, zb, eb, z_sq, e_sq);
    transpose_bf16<<<dim3(N_EXP / 64, D_DIM / 64), 256, 0, stream>>>(eb, ebT);

    // GEMM1: sim -> out (nt), bf16(exp(sim)) -> Wb, partial rowsums
    gemm_bt<1><<<(M_TOK / 128) * (N_EXP / 128), 512, 0, stream>>>(
        zb, eb, M_TOK, N_EXP, D_DIM, sim, N_EXP, z_sq, e_sq, rs_part, Wb, nullptr);

    // GEMM2: wout = (Wb @ E) / rowsum; rowsum reduced in-kernel from rs_part
    gemm_bt<0><<<(M_TOK / 128) * (D_DIM / 128), 512, 0, stream>>>(
        Wb, ebT, M_TOK, D_DIM, N_EXP, wout, D_DIM, nullptr, nullptr, rs_part,
        nullptr, nullptr);
  } else {
    // fallback: zb aliases Wb, separate weights pass (round-9 style)
    u16* Wb  = (u16*)ws;                              // 64 MiB
    u16* zb  = (u16*)ws;                              // aliases Wb
    u16* eb  = (u16*)(ws + 64 * MB);                  // 8 MiB
    u16* ebT = (u16*)(ws + 72 * MB);                  // 8 MiB
    float* rs_part = (float*)(ws + 80 * MB);          // 4 MiB
    float* z_sq   = (float*)(ws + 84 * MB);
    float* e_sq   = (float*)(ws + 84 * MB + 32768);
    float* rowsum = (float*)(ws + 84 * MB + 49152);

    prep_convert2<<<M_TOK + N_EXP, 256, 0, stream>>>(z, e, zb, eb, z_sq, e_sq);
    transpose_bf16<<<dim3(N_EXP / 64, D_DIM / 64), 256, 0, stream>>>(eb, ebT);

    gemm_bt<1><<<(M_TOK / 128) * (N_EXP / 128), 512, 0, stream>>>(
        zb, eb, M_TOK, N_EXP, D_DIM, sim, N_EXP, z_sq, e_sq, rs_part,
        nullptr, nullptr);

    rowsum_reduce<<<M_TOK / 256, 256, 0, stream>>>(rs_part, rowsum);

    weights_kernel<<<(M_TOK * (size_t)N_EXP) / (8 * 256), 256, 0, stream>>>(sim, rowsum, Wb);

    gemm_bt<0><<<(M_TOK / 128) * (D_DIM / 128), 512, 0, stream>>>(
        Wb, ebT, M_TOK, D_DIM, N_EXP, wout, D_DIM, nullptr, nullptr, nullptr,
        nullptr, nullptr);
  }
}